// Round 6
// baseline (199.332 us; speedup 1.0000x reference)
//
#include <hip/hip_runtime.h>
#include <math.h>

#define EPS 1e-8f
#define HALF_BIN 0.05f

#define TILE 512                       // elements per tile
#define BUF_FLOATS (11 * TILE)         // 5632 floats = 22 KB per buffer
#define SMEM_FLOATS (2 * BUF_FLOATS)   // 44 KB total -> 3 blocks/CU

typedef float v2f __attribute__((ext_vector_type(2)));

// pd = sigmoid(xu) - sigmoid(xl) with one reciprocal (verified absmax 0.0 in R2-R5)
__device__ __forceinline__ float sigmoid_diff(float xu, float xl) {
    float eu = __expf(fminf(-xu, 87.0f));
    float el = __expf(fminf(-xl, 87.0f));
    return __fdividef(el - eu, (1.0f + eu) * (1.0f + el));
}

// One wave-level direct-to-LDS load: 64 lanes x 16 B = 1 KB global -> 1 KB LDS.
// LDS dest is wave-uniform base + lane*16 (HW rule), gsrc is per-lane.
__device__ __forceinline__ void ld_unit(const float* gsrc, float* ldst_uniform) {
    __builtin_amdgcn_global_load_lds(
        (const __attribute__((address_space(1))) void*)gsrc,
        (__attribute__((address_space(3))) void*)ldst_uniform,
        16, 0, 0);
}

// LDS layout per buffer (floats): array a occupies [a*512, a*512+512)
//  a: 0=p 1=tv 2=mu0 3=sg0 4=wt0 5=mu1 6=sg1 7=wt1 8=mu2 9=sg2 10=wt2
// 22 one-KB units; waves 0,1 issue 6 units, waves 2,3 issue 5 (all constants
// per branch so no dynamic pointer indexing -> no scratch).
__device__ __forceinline__ void issue_tile(
    const float* p, const float* tv,
    const float* mu0, const float* sg0, const float* wt0,
    const float* mu1, const float* sg1, const float* wt1,
    const float* mu2, const float* sg2, const float* wt2,
    float* lb, int tstart, int wave, int lane)
{
    const int l4 = lane * 4;
    if (wave == 0) {
        ld_unit(p   + tstart       + l4, lb + 0);
        ld_unit(p   + tstart + 256 + l4, lb + 256);
        ld_unit(tv  + tstart       + l4, lb + 512);
        ld_unit(tv  + tstart + 256 + l4, lb + 768);
        ld_unit(mu0 + tstart       + l4, lb + 1024);
        ld_unit(mu0 + tstart + 256 + l4, lb + 1280);
    } else if (wave == 1) {
        ld_unit(sg0 + tstart       + l4, lb + 1536);
        ld_unit(sg0 + tstart + 256 + l4, lb + 1792);
        ld_unit(wt0 + tstart       + l4, lb + 2048);
        ld_unit(wt0 + tstart + 256 + l4, lb + 2304);
        ld_unit(mu1 + tstart       + l4, lb + 2560);
        ld_unit(mu1 + tstart + 256 + l4, lb + 2816);
    } else if (wave == 2) {
        ld_unit(sg1 + tstart       + l4, lb + 3072);
        ld_unit(sg1 + tstart + 256 + l4, lb + 3328);
        ld_unit(wt1 + tstart       + l4, lb + 3584);
        ld_unit(wt1 + tstart + 256 + l4, lb + 3840);
        ld_unit(mu2 + tstart       + l4, lb + 4096);
    } else {
        ld_unit(mu2 + tstart + 256 + l4, lb + 4352);
        ld_unit(sg2 + tstart       + l4, lb + 4608);
        ld_unit(sg2 + tstart + 256 + l4, lb + 4864);
        ld_unit(wt2 + tstart       + l4, lb + 5120);
        ld_unit(wt2 + tstart + 256 + l4, lb + 5376);
    }
}

__global__ __launch_bounds__(256) void zimol_main_k3(
    const float* __restrict__ p,
    const float* __restrict__ mu,
    const float* __restrict__ sigma,
    const float* __restrict__ weight,
    const float* __restrict__ tv,
    float* __restrict__ part_bce,
    float* __restrict__ part_ll,
    float* __restrict__ part_n,
    int B)
{
    __shared__ float smem[SMEM_FLOATS];

    const int wave = threadIdx.x >> 6;
    const int lane = threadIdx.x & 63;
    const int nt   = B / TILE;
    const int G    = gridDim.x;

    const float* mu0 = mu;
    const float* mu1 = mu + (size_t)B;
    const float* mu2 = mu + 2 * (size_t)B;
    const float* sg0 = sigma;
    const float* sg1 = sigma + (size_t)B;
    const float* sg2 = sigma + 2 * (size_t)B;
    const float* wt0 = weight;
    const float* wt1 = weight + (size_t)B;
    const float* wt2 = weight + 2 * (size_t)B;

    float bce = 0.0f, ll = 0.0f, npaid = 0.0f;

    int t   = blockIdx.x;
    int buf = 0;
    if (t < nt)
        issue_tile(p, tv, mu0, sg0, wt0, mu1, sg1, wt1, mu2, sg2, wt2,
                   smem, t * TILE, wave, lane);

    for (; t < nt; t += G) {
        const int tn = t + G;
        if (tn < nt) {
            issue_tile(p, tv, mu0, sg0, wt0, mu1, sg1, wt1, mu2, sg2, wt2,
                       smem + (buf ^ 1) * BUF_FLOATS, tn * TILE, wave, lane);
            // wait for current tile only: <= (next tile's own issues) left pending
            if (wave < 2) asm volatile("s_waitcnt vmcnt(6)" ::: "memory");
            else          asm volatile("s_waitcnt vmcnt(5)" ::: "memory");
        } else {
            asm volatile("s_waitcnt vmcnt(0)" ::: "memory");
        }
        // raw barrier (NOT __syncthreads: that drains vmcnt(0) and kills prefetch)
        asm volatile("s_barrier" ::: "memory");

        const float* lb = smem + buf * BUF_FLOATS;
        const int e = 2 * threadIdx.x;

        v2f P = *(const v2f*)(lb + 0   + e);
        v2f T = *(const v2f*)(lb + 512 + e);
        v2f M[3], S[3], W[3];
        M[0] = *(const v2f*)(lb + 1024 + e);
        S[0] = *(const v2f*)(lb + 1536 + e);
        W[0] = *(const v2f*)(lb + 2048 + e);
        M[1] = *(const v2f*)(lb + 2560 + e);
        S[1] = *(const v2f*)(lb + 3072 + e);
        W[1] = *(const v2f*)(lb + 3584 + e);
        M[2] = *(const v2f*)(lb + 4096 + e);
        S[2] = *(const v2f*)(lb + 4608 + e);
        W[2] = *(const v2f*)(lb + 5120 + e);

        float lik[2] = {0.0f, 0.0f};
        #pragma unroll
        for (int k = 0; k < 3; ++k) {
            #pragma unroll
            for (int j = 0; j < 2; ++j) {
                float inv_s = __fdividef(1.0f, S[k][j] + EPS);
                float xu = (T[j] + HALF_BIN - M[k][j]) * inv_s;
                float xl = (T[j] - HALF_BIN - M[k][j]) * inv_s;
                float pd = fmaxf(sigmoid_diff(xu, xl), EPS);
                lik[j] = fmaf(W[k][j], pd, lik[j]);
            }
        }
        #pragma unroll
        for (int j = 0; j < 2; ++j) {
            bool paid = T[j] > 0.0f;
            float val = paid ? P[j] : (1.0f - P[j]);
            bce -= fmaxf(__logf(val), -100.0f);
            float lg = __logf(lik[j] + EPS);
            ll    += paid ? lg : 0.0f;
            npaid += paid ? 1.0f : 0.0f;
        }

        // all LDS reads done before next issue overwrites this buffer
        asm volatile("s_waitcnt lgkmcnt(0)" ::: "memory");
        asm volatile("s_barrier" ::: "memory");
        buf ^= 1;
    }

    #pragma unroll
    for (int off = 32; off > 0; off >>= 1) {
        bce   += __shfl_down(bce,   off, 64);
        ll    += __shfl_down(ll,    off, 64);
        npaid += __shfl_down(npaid, off, 64);
    }
    __shared__ float sdata[3][4];
    if (lane == 0) {
        sdata[0][wave] = bce; sdata[1][wave] = ll; sdata[2][wave] = npaid;
    }
    __syncthreads();
    if (threadIdx.x == 0) {
        float b = 0.0f, l = 0.0f, n = 0.0f;
        #pragma unroll
        for (int w = 0; w < 4; ++w) {
            b += sdata[0][w]; l += sdata[1][w]; n += sdata[2][w];
        }
        part_bce[blockIdx.x] = b;
        part_ll [blockIdx.x] = l;
        part_n  [blockIdx.x] = n;
    }
}

// ---- generic fallback (any K, any B) ----
template <int K>
__global__ __launch_bounds__(256) void zimol_main_gen(
    const float* __restrict__ p,
    const float* __restrict__ mu,
    const float* __restrict__ sigma,
    const float* __restrict__ weight,
    const float* __restrict__ tv,
    float* __restrict__ part_bce,
    float* __restrict__ part_ll,
    float* __restrict__ part_n,
    int B)
{
    const int tid    = blockIdx.x * blockDim.x + threadIdx.x;
    const int stride = gridDim.x * blockDim.x;

    float bce = 0.0f, ll = 0.0f, npaid = 0.0f;

    for (int i = tid; i < B; i += stride) {
        float t = tv[i];
        float lik = 0.0f;
        #pragma unroll
        for (int k = 0; k < K; ++k) {
            size_t off = (size_t)k * (size_t)B + (size_t)i;
            float inv_s = __fdividef(1.0f, sigma[off] + EPS);
            float xu = (t + HALF_BIN - mu[off]) * inv_s;
            float xl = (t - HALF_BIN - mu[off]) * inv_s;
            float pd = fmaxf(sigmoid_diff(xu, xl), EPS);
            lik = fmaf(weight[off], pd, lik);
        }
        bool paid = t > 0.0f;
        float val = paid ? p[i] : (1.0f - p[i]);
        bce -= fmaxf(__logf(val), -100.0f);
        float lg = __logf(lik + EPS);
        ll    += paid ? lg : 0.0f;
        npaid += paid ? 1.0f : 0.0f;
    }

    #pragma unroll
    for (int off = 32; off > 0; off >>= 1) {
        bce   += __shfl_down(bce,   off, 64);
        ll    += __shfl_down(ll,    off, 64);
        npaid += __shfl_down(npaid, off, 64);
    }
    __shared__ float sdata[3][4];
    const int wave = threadIdx.x >> 6;
    const int lane = threadIdx.x & 63;
    if (lane == 0) {
        sdata[0][wave] = bce; sdata[1][wave] = ll; sdata[2][wave] = npaid;
    }
    __syncthreads();
    if (threadIdx.x == 0) {
        float b = 0.0f, l = 0.0f, n = 0.0f;
        #pragma unroll
        for (int w = 0; w < 4; ++w) {
            b += sdata[0][w]; l += sdata[1][w]; n += sdata[2][w];
        }
        part_bce[blockIdx.x] = b;
        part_ll [blockIdx.x] = l;
        part_n  [blockIdx.x] = n;
    }
}

__global__ __launch_bounds__(256) void zimol_reduce(
    const float* __restrict__ part_bce,
    const float* __restrict__ part_ll,
    const float* __restrict__ part_n,
    float* __restrict__ out, int nblocks, int B)
{
    double b = 0.0, l = 0.0, n = 0.0;
    for (int i = threadIdx.x; i < nblocks; i += 256) {
        b += (double)part_bce[i];
        l += (double)part_ll[i];
        n += (double)part_n[i];
    }
    #pragma unroll
    for (int off = 32; off > 0; off >>= 1) {
        b += __shfl_down(b, off, 64);
        l += __shfl_down(l, off, 64);
        n += __shfl_down(n, off, 64);
    }
    __shared__ double sdata[3][4];
    const int wave = threadIdx.x >> 6;
    const int lane = threadIdx.x & 63;
    if (lane == 0) {
        sdata[0][wave] = b; sdata[1][wave] = l; sdata[2][wave] = n;
    }
    __syncthreads();
    if (threadIdx.x == 0) {
        double tb = 0.0, tl = 0.0, tn = 0.0;
        #pragma unroll
        for (int w = 0; w < 4; ++w) {
            tb += sdata[0][w]; tl += sdata[1][w]; tn += sdata[2][w];
        }
        double purchase = tb / (double)B;
        double ltv = (tn > 0.0) ? -(tl / fmax(tn, 1.0)) : 0.0;
        out[0] = (float)(purchase + ltv);
    }
}

extern "C" void kernel_launch(void* const* d_in, const int* in_sizes, int n_in,
                              void* d_out, int out_size, void* d_ws, size_t ws_size,
                              hipStream_t stream) {
    const float* p      = (const float*)d_in[0];
    const float* mu     = (const float*)d_in[1];
    const float* sigma  = (const float*)d_in[2];
    const float* weight = (const float*)d_in[3];
    const float* tv     = (const float*)d_in[4];
    float* out = (float*)d_out;

    const int B = in_sizes[0];
    const int K = in_sizes[1] / B;

    const int threads = 256;
    float* part_bce = (float*)d_ws;

    if (K == 3 && (B % TILE) == 0) {
        int nt = B / TILE;
        int blocks = 768;               // 3 blocks/CU at 44 KB LDS
        if (blocks > nt) blocks = nt;
        float* part_ll = part_bce + blocks;
        float* part_n  = part_ll  + blocks;
        zimol_main_k3<<<blocks, threads, 0, stream>>>(
            p, mu, sigma, weight, tv, part_bce, part_ll, part_n, B);
        zimol_reduce<<<1, threads, 0, stream>>>(part_bce, part_ll, part_n, out, blocks, B);
    } else {
        int blocks = (B + threads - 1) / threads;
        if (blocks > 2048) blocks = 2048;
        if (blocks < 1) blocks = 1;
        float* part_ll = part_bce + blocks;
        float* part_n  = part_ll  + blocks;
        if (K == 1) {
            zimol_main_gen<1><<<blocks, threads, 0, stream>>>(
                p, mu, sigma, weight, tv, part_bce, part_ll, part_n, B);
        } else if (K == 2) {
            zimol_main_gen<2><<<blocks, threads, 0, stream>>>(
                p, mu, sigma, weight, tv, part_bce, part_ll, part_n, B);
        } else if (K == 3) {
            zimol_main_gen<3><<<blocks, threads, 0, stream>>>(
                p, mu, sigma, weight, tv, part_bce, part_ll, part_n, B);
        } else {
            zimol_main_gen<4><<<blocks, threads, 0, stream>>>(
                p, mu, sigma, weight, tv, part_bce, part_ll, part_n, B);
        }
        zimol_reduce<<<1, threads, 0, stream>>>(part_bce, part_ll, part_n, out, blocks, B);
    }
}